// Round 6
// baseline (160.998 us; speedup 1.0000x reference)
//
#include <hip/hip_runtime.h>

typedef __attribute__((ext_vector_type(8))) short short8;
typedef __attribute__((ext_vector_type(4))) float float4v;
typedef __attribute__((ext_vector_type(4))) unsigned short us4;
typedef __attribute__((address_space(3))) unsigned int as3u32;
typedef __attribute__((address_space(1))) unsigned int as1u32;

#define DIN 128
#define SSIZE 1024
#define MLGK 256
#define DOUT 10
#define TM 64   // x-rows per block; 4 waves x 16 rows
#define TS 64   // anchors per staged tile
#define NT 16   // anchor tiles

__device__ inline unsigned short f2bf(float f) {  // RNE (bit-exact R4 path)
  unsigned int u = __float_as_uint(f);
  u = (u + 0x7FFFu + ((u >> 16) & 1u)) >> 16;
  return (unsigned short)u;
}
__device__ inline float bf2f(unsigned short h) {
  return __uint_as_float(((unsigned int)h) << 16);
}
__device__ inline float mish_f(float x) {
  if (x > 30.f) return x;
  float e = __expf(x);
  float u = 1.f + e;
  float u2 = u * u;
  return x * (u2 - 1.f) / (u2 + 1.f);
}
// element-index XOR swizzle; identical to the chunk-XOR used by stage64
__device__ inline int swz(int row, int col) {
  return row * DIN + (col ^ ((row & 7) << 3));
}

// Stage a 64x128 bf16 tile (row stride DIN) into a 16KB LDS region via
// global_load_lds width=16. LDS dest LINEAR in lane order (rule #21); the XOR
// swizzle is applied by permuting the GLOBAL source chunk.
__device__ inline void stage64(const unsigned short* __restrict__ gsrc,
                               unsigned short* region, int tid) {
#pragma unroll
  for (int it = 0; it < 4; ++it) {
    int slot = it * 256 + tid;
    int r = slot >> 4;
    int c8 = (slot & 15) ^ (r & 7);
    __builtin_amdgcn_global_load_lds((const as1u32*)(gsrc + r * DIN + c8 * 8),
                                     (as3u32*)(region + slot * 8), 16, 0, 0);
  }
}

// ---------- single fused precompute kernel ----------
// blocks 0..191: bf16 weight conversion (W1b, W2b, padded Wcb).
// blocks 192..223: anchor pipeline, 32 anchors/block, f32 math block-locally:
//   tanh(Wa@mlg) -> mish-encode x2 -> bf16 ancb + a2 (from rounded values).

__global__ __launch_bounds__(256) void k_pre(
    const float* __restrict__ W1, const float* __restrict__ W2,
    const float* __restrict__ Wc, const float* __restrict__ Wa,
    const float* __restrict__ mlg, const float* __restrict__ b1,
    const float* __restrict__ b2,
    unsigned short* W1b, unsigned short* W2b, unsigned short* Wcb,
    unsigned short* ancb, float* a2) {
  const int blk = blockIdx.x;
  const int tid = threadIdx.x;
  if (blk < 192) {
    int i = blk * 256 + tid;  // 49152 total
    if (i < 16384) {
      W1b[i] = f2bf(W1[i]);
    } else if (i < 32768) {
      W2b[i - 16384] = f2bf(W2[i - 16384]);
    } else {
      int j = i - 32768;  // [16][1024] padded Wc (rows >= DOUT zero)
      int o = j >> 10;
      int s = j & 1023;
      Wcb[j] = (o < DOUT) ? f2bf(Wc[o * SSIZE + s]) : (unsigned short)0;
    }
    return;
  }
  __shared__ float A[32][DIN];
  __shared__ float B[32][DIN];
  const int s0 = (blk - 192) * 32;
  const int d = tid & 127;
  const int sg = tid >> 7;  // thread owns column d for 16 anchors sg*16+si

  // phase 1: B = tanh(Wa @ mlg)
  {
    float acc[16];
#pragma unroll
    for (int si = 0; si < 16; ++si) acc[si] = 0.f;
    const float* wr0 = Wa + (size_t)(s0 + sg * 16) * MLGK;
    for (int k = 0; k < MLGK; ++k) {
      float m = mlg[k * DIN + d];
#pragma unroll
      for (int si = 0; si < 16; ++si) acc[si] = fmaf(wr0[si * MLGK + k], m, acc[si]);
    }
#pragma unroll
    for (int si = 0; si < 16; ++si) B[sg * 16 + si][d] = tanhf(acc[si]);
  }
  __syncthreads();
  // phase 2: A = mish(B @ W1^T + b1)
  {
    float acc[16];
#pragma unroll
    for (int si = 0; si < 16; ++si) acc[si] = 0.f;
    const float* w = W1 + d * DIN;
    for (int k = 0; k < DIN; ++k) {
      float wv = w[k];
#pragma unroll
      for (int si = 0; si < 16; ++si) acc[si] = fmaf(B[sg * 16 + si][k], wv, acc[si]);
    }
    float bv = b1[d];
#pragma unroll
    for (int si = 0; si < 16; ++si) A[sg * 16 + si][d] = mish_f(acc[si] + bv);
  }
  __syncthreads();
  // phase 3: B = mish(A @ W2^T + b2)
  {
    float acc[16];
#pragma unroll
    for (int si = 0; si < 16; ++si) acc[si] = 0.f;
    const float* w = W2 + d * DIN;
    for (int k = 0; k < DIN; ++k) {
      float wv = w[k];
#pragma unroll
      for (int si = 0; si < 16; ++si) acc[si] = fmaf(A[sg * 16 + si][k], wv, acc[si]);
    }
    float bv = b2[d];
#pragma unroll
    for (int si = 0; si < 16; ++si) B[sg * 16 + si][d] = mish_f(acc[si] + bv);
  }
  __syncthreads();
  // phase 4: ancb (bf16 RNE) + a2 from the ROUNDED values
  for (int idx = tid; idx < 32 * DIN; idx += 256) {
    int s = idx >> 7, dd = idx & 127;
    ancb[(size_t)(s0 + s) * DIN + dd] = f2bf(B[s][dd]);
  }
  __syncthreads();
  if (tid < 32) {
    float acc = 0.f;
    for (int dd = 0; dd < DIN; ++dd) {
      float v = bf2f(f2bf(B[tid][dd]));
      acc = fmaf(v, v, acc);
    }
    a2[s0 + tid] = acc;
  }
}

// ---------- fused main kernel (R4-proven numerics + setprio hint) ----------

__global__ __launch_bounds__(256, 4) void k_main(
    const float* __restrict__ x, const float* __restrict__ b1,
    const float* __restrict__ b2, const float* __restrict__ bc,
    const unsigned short* __restrict__ W1b, const unsigned short* __restrict__ W2b,
    const unsigned short* __restrict__ Wcb, const unsigned short* __restrict__ ancb,
    const float* __restrict__ a2, float* __restrict__ out) {
  __shared__ __align__(16) unsigned short reg0[TM * DIN];  // h/x_dml; anchor buf A
  __shared__ __align__(16) unsigned short reg1[TM * DIN];  // W halves; anchor buf B
  __shared__ __align__(16) float ldsa2[SSIZE];

  const int tid = threadIdx.x;
  const int lane = tid & 63;
  const int l15 = lane & 15;
  const int lhi = lane >> 4;
  const int n0 = blockIdx.x * TM;
  const int rbase = (tid >> 6) * 16;

  for (int i = tid; i < SSIZE; i += 256) ldsa2[i] = a2[i];

  // ---- x rows -> bf16 A-fragments (global -> reg) ----
  short8 af[4];
#pragma unroll
  for (int kk = 0; kk < 4; ++kk) {
    const float* p = x + (size_t)(n0 + rbase + l15) * DIN + kk * 32 + lhi * 8;
    float4 u = *(const float4*)p;
    float4 v = *(const float4*)(p + 4);
    short8 a;
    a[0] = f2bf(u.x); a[1] = f2bf(u.y); a[2] = f2bf(u.z); a[3] = f2bf(u.w);
    a[4] = f2bf(v.x); a[5] = f2bf(v.y); a[6] = f2bf(v.z); a[7] = f2bf(v.w);
    af[kk] = a;
  }

  // ---- encode: 2 layers x 2 staged 64-col halves of W ----
#pragma unroll 1
  for (int layer = 0; layer < 2; ++layer) {
    const unsigned short* Wb = layer ? W2b : W1b;
    const float* bias = layer ? b2 : b1;
    short8 ah[4];
#pragma unroll
    for (int kk = 0; kk < 4; ++kk)
      ah[kk] = layer ? *(const short8*)&reg0[swz(rbase + l15, kk * 32 + lhi * 8)]
                     : af[kk];
#pragma unroll 1
    for (int half = 0; half < 2; ++half) {
      stage64(Wb + (size_t)(half * 64) * DIN, reg1, tid);
      __syncthreads();  // W half staged (vmcnt drained by barrier)
      float4v acc[4];
#pragma unroll
      for (int ct = 0; ct < 4; ++ct) acc[ct] = (float4v){0.f, 0.f, 0.f, 0.f};
#pragma unroll
      for (int kk = 0; kk < 4; ++kk) {
        int k = kk * 32 + lhi * 8;
#pragma unroll
        for (int ct = 0; ct < 4; ++ct) {
          short8 b = *(const short8*)&reg1[swz(ct * 16 + l15, k)];
          acc[ct] = __builtin_amdgcn_mfma_f32_16x16x32_bf16(ah[kk], b, acc[ct], 0, 0, 0);
        }
      }
      __syncthreads();  // all waves done reading reg1 before next stage
#pragma unroll
      for (int ct = 0; ct < 4; ++ct) {
        int col = half * 64 + ct * 16 + l15;
        float bv = bias[col];
#pragma unroll
        for (int j = 0; j < 4; ++j) {
          float m = mish_f(acc[ct][j] + bv);
          reg0[swz(rbase + lhi * 4 + j, col)] = f2bf(m);  // wave-private rows
        }
      }
    }
  }

  // ---- hoist x_dml B-fragments; row norm from the rounded registers ----
  short8 bx[4];
#pragma unroll
  for (int kk = 0; kk < 4; ++kk)
    bx[kk] = *(const short8*)&reg0[swz(rbase + l15, kk * 32 + lhi * 8)];
  float x2v = 0.f;
#pragma unroll
  for (int kk = 0; kk < 4; ++kk)
#pragma unroll
    for (int e = 0; e < 8; ++e) {
      float v = bf2f((unsigned short)bx[kk][e]);
      x2v = fmaf(v, v, x2v);
    }
  x2v += __shfl_xor(x2v, 16);
  x2v += __shfl_xor(x2v, 32);   // full row-norm of row rbase+l15
  __syncthreads();              // everyone done with reg0 before anchor staging

  // ---- distance + in-register logits over 16 anchor tiles of 64 ----
  float4v lacc[2];
  lacc[0] = (float4v){0.f, 0.f, 0.f, 0.f};
  lacc[1] = (float4v){0.f, 0.f, 0.f, 0.f};
  const unsigned short* wcrow = Wcb + l15 * SSIZE;

  auto dist_tile = [&](const unsigned short* buf, int t) {
    float4v acc[4];
#pragma unroll
    for (int ct = 0; ct < 4; ++ct) acc[ct] = (float4v){0.f, 0.f, 0.f, 0.f};
    __builtin_amdgcn_s_setprio(1);
#pragma unroll
    for (int kk = 0; kk < 4; ++kk) {
      int k = kk * 32 + lhi * 8;
#pragma unroll
      for (int ct = 0; ct < 4; ++ct) {
        short8 a = *(const short8*)&buf[swz(ct * 16 + l15, k)];
        acc[ct] = __builtin_amdgcn_mfma_f32_16x16x32_bf16(a, bx[kk], acc[ct], 0, 0, 0);
      }
    }
    __builtin_amdgcn_s_setprio(0);
#pragma unroll
    for (int ct = 0; ct < 4; ++ct) {
      int sb = t * TS + ct * 16 + lhi * 4;
      float4 av = *(const float4*)&ldsa2[sb];
      us4 w4 = *(const us4*)&wcrow[sb];
      unsigned short db[4];
#pragma unroll
      for (int j = 0; j < 4; ++j) {
        float sqv = fmaf(-2.f, acc[ct][j], x2v + (&av.x)[j]);
        db[j] = f2bf(sqrtf(fmaxf(sqv, 0.f)));
      }
      short8 a8 = {(short)w4[0], (short)w4[1], (short)w4[2], (short)w4[3], 0, 0, 0, 0};
      short8 b8 = {(short)db[0], (short)db[1], (short)db[2], (short)db[3], 0, 0, 0, 0};
      lacc[ct & 1] = __builtin_amdgcn_mfma_f32_16x16x32_bf16(a8, b8, lacc[ct & 1], 0, 0, 0);
    }
  };

  stage64(ancb, reg0, tid);  // tile 0
  __syncthreads();
#pragma unroll 1
  for (int tp = 0; tp < NT / 2; ++tp) {
    stage64(ancb + (size_t)(2 * tp + 1) * TS * DIN, reg1, tid);  // in flight over compute
    dist_tile(reg0, 2 * tp);
    __syncthreads();
    if (tp < NT / 2 - 1)
      stage64(ancb + (size_t)(2 * tp + 2) * TS * DIN, reg0, tid);
    dist_tile(reg1, 2 * tp + 1);
    __syncthreads();
  }
  float4v L = lacc[0] + lacc[1];

  // ---- bias + log_softmax + store (lane holds logits[lhi*4+j][row l15]) ----
  {
    const int xrow = n0 + rbase + l15;
    float v[4];
    float m4 = -1e30f;
#pragma unroll
    for (int j = 0; j < 4; ++j) {
      int o = lhi * 4 + j;
      v[j] = (o < DOUT) ? (L[j] + bc[o]) : -1e30f;
      m4 = fmaxf(m4, v[j]);
    }
    m4 = fmaxf(m4, __shfl_xor(m4, 16));
    m4 = fmaxf(m4, __shfl_xor(m4, 32));
    float es = 0.f;
#pragma unroll
    for (int j = 0; j < 4; ++j) {
      int o = lhi * 4 + j;
      es += (o < DOUT) ? __expf(v[j] - m4) : 0.f;
    }
    es += __shfl_xor(es, 16);
    es += __shfl_xor(es, 32);
    float ls = logf(es);
#pragma unroll
    for (int j = 0; j < 4; ++j) {
      int o = lhi * 4 + j;
      if (o < DOUT) out[(size_t)xrow * DOUT + o] = v[j] - m4 - ls;
    }
  }
}

extern "C" void kernel_launch(void* const* d_in, const int* in_sizes, int n_in,
                              void* d_out, int out_size, void* d_ws, size_t ws_size,
                              hipStream_t stream) {
  const float* x   = (const float*)d_in[0];
  const float* mlg = (const float*)d_in[1];
  const float* W1  = (const float*)d_in[2];
  const float* b1  = (const float*)d_in[3];
  const float* W2  = (const float*)d_in[4];
  const float* b2  = (const float*)d_in[5];
  const float* Wa  = (const float*)d_in[6];
  const float* Wc  = (const float*)d_in[7];
  const float* bc  = (const float*)d_in[8];
  float* out = (float*)d_out;

  // workspace layout (~0.36 MB total)
  unsigned short* W1b  = (unsigned short*)d_ws;        // 16384 bf16
  unsigned short* W2b  = W1b + 16384;                  // 16384 bf16
  unsigned short* Wcb  = W2b + 16384;                  // 16*1024 bf16 (zero-padded)
  unsigned short* ancb = Wcb + 16384;                  // 1024*128 bf16
  float* a2 = (float*)(ancb + SSIZE * DIN);            // 1024 f32

  k_pre<<<224, 256, 0, stream>>>(W1, W2, Wc, Wa, mlg, b1, b2,
                                 W1b, W2b, Wcb, ancb, a2);
  k_main<<<1024, 256, 0, stream>>>(x, b1, b2, bc, W1b, W2b, Wcb, ancb, a2, out);
}

// Round 7
// 106.426 us; speedup vs baseline: 1.5128x; 1.5128x over previous
//
#include <hip/hip_runtime.h>

typedef __attribute__((ext_vector_type(8))) short short8;
typedef __attribute__((ext_vector_type(4))) float float4v;
typedef __attribute__((ext_vector_type(4))) unsigned short us4;
typedef __attribute__((address_space(3))) unsigned int as3u32;
typedef __attribute__((address_space(1))) unsigned int as1u32;

#define DIN 128
#define SSIZE 1024
#define MLGK 256
#define DOUT 10
#define TM 64   // x-rows per block; 4 waves x 16 rows
#define TS 64   // anchors per staged tile
#define NT 16   // anchor tiles

__device__ inline unsigned short f2bf(float f) {  // RNE (bit-exact proven path)
  unsigned int u = __float_as_uint(f);
  u = (u + 0x7FFFu + ((u >> 16) & 1u)) >> 16;
  return (unsigned short)u;
}
__device__ inline float bf2f(unsigned short h) {
  return __uint_as_float(((unsigned int)h) << 16);
}
__device__ inline float mish_f(float x) {
  if (x > 30.f) return x;
  float e = __expf(x);
  float u = 1.f + e;
  float u2 = u * u;
  return x * (u2 - 1.f) / (u2 + 1.f);
}
// element-index XOR swizzle; identical to the chunk-XOR used by stage64
__device__ inline int swz(int row, int col) {
  return row * DIN + (col ^ ((row & 7) << 3));
}

// Stage a 64x128 bf16 tile (row stride DIN) into a 16KB LDS region via
// global_load_lds width=16. LDS dest LINEAR in lane order (rule #21); the XOR
// swizzle is applied by permuting the GLOBAL source chunk.
__device__ inline void stage64(const unsigned short* __restrict__ gsrc,
                               unsigned short* region, int tid) {
#pragma unroll
  for (int it = 0; it < 4; ++it) {
    int slot = it * 256 + tid;
    int r = slot >> 4;
    int c8 = (slot & 15) ^ (r & 7);
    __builtin_amdgcn_global_load_lds((const as1u32*)(gsrc + r * DIN + c8 * 8),
                                     (as3u32*)(region + slot * 8), 16, 0, 0);
  }
}

// ---------- wide precompute kernels (fp32, one element per thread) ----------

// blocks 0..191: weights -> bf16. blocks 192..703: anc_raw = tanh(Wa @ mlg).
__global__ __launch_bounds__(256) void k_pre1(
    const float* __restrict__ W1, const float* __restrict__ W2,
    const float* __restrict__ Wc, const float* __restrict__ Wa,
    const float* __restrict__ mlg,
    unsigned short* W1b, unsigned short* W2b, unsigned short* Wcb,
    float* anc_raw) {
  const int blk = blockIdx.x;
  const int tid = threadIdx.x;
  if (blk < 192) {
    int i = blk * 256 + tid;  // 49152 total
    if (i < 16384) {
      W1b[i] = f2bf(W1[i]);
    } else if (i < 32768) {
      W2b[i - 16384] = f2bf(W2[i - 16384]);
    } else {
      int j = i - 32768;  // [16][1024] padded Wc (rows >= DOUT zero)
      int o = j >> 10;
      int s = j & 1023;
      Wcb[j] = (o < DOUT) ? f2bf(Wc[o * SSIZE + s]) : (unsigned short)0;
    }
    return;
  }
  int i = (blk - 192) * 256 + tid;  // 1024*128
  int s = i >> 7, d = i & 127;
  float acc = 0.f;
  for (int k = 0; k < MLGK; ++k) acc = fmaf(Wa[s * MLGK + k], mlg[k * DIN + d], acc);
  anc_raw[i] = tanhf(acc);
}

// anc_h = mish(anc_raw @ W1^T + b1)
__global__ __launch_bounds__(256) void k_pre2(const float* __restrict__ anc_raw,
                                              const float* __restrict__ W1,
                                              const float* __restrict__ b1,
                                              float* anc_h) {
  int i = blockIdx.x * 256 + threadIdx.x;  // 1024*128
  int r = i >> 7, d = i & 127;
  float acc = 0.f;
  const float* a = anc_raw + r * DIN;
  const float* w = W1 + d * DIN;
  for (int k = 0; k < DIN; ++k) acc = fmaf(a[k], w[k], acc);
  anc_h[i] = mish_f(acc + b1[d]);
}

// ancb = bf16(mish(anc_h @ W2^T + b2)); a2 = rownorm2 of the ROUNDED values.
// 2 anchor rows per block (256 threads = 2 x 128 cols).
__global__ __launch_bounds__(256) void k_pre3(const float* __restrict__ anc_h,
                                              const float* __restrict__ W2,
                                              const float* __restrict__ b2,
                                              unsigned short* ancb, float* a2) {
  __shared__ float part[4];
  const int tid = threadIdx.x;
  const int row = blockIdx.x * 2 + (tid >> 7);
  const int d = tid & 127;
  float acc = 0.f;
  const float* a = anc_h + (size_t)row * DIN;
  const float* w = W2 + d * DIN;
  for (int k = 0; k < DIN; ++k) acc = fmaf(a[k], w[k], acc);
  unsigned short mb = f2bf(mish_f(acc + b2[d]));
  ancb[(size_t)row * DIN + d] = mb;
  float v = bf2f(mb);
  float p = v * v;
  p += __shfl_xor(p, 1);  p += __shfl_xor(p, 2);  p += __shfl_xor(p, 4);
  p += __shfl_xor(p, 8);  p += __shfl_xor(p, 16); p += __shfl_xor(p, 32);
  if ((tid & 63) == 0) part[tid >> 6] = p;
  __syncthreads();
  if (tid == 0)   a2[row]     = part[0] + part[1];
  if (tid == 128) a2[row]     = part[2] + part[3];
}

// ---------- fused main kernel (R6-proven: R4 numerics + setprio) ----------

__global__ __launch_bounds__(256, 4) void k_main(
    const float* __restrict__ x, const float* __restrict__ b1,
    const float* __restrict__ b2, const float* __restrict__ bc,
    const unsigned short* __restrict__ W1b, const unsigned short* __restrict__ W2b,
    const unsigned short* __restrict__ Wcb, const unsigned short* __restrict__ ancb,
    const float* __restrict__ a2, float* __restrict__ out) {
  __shared__ __align__(16) unsigned short reg0[TM * DIN];  // h/x_dml; anchor buf A
  __shared__ __align__(16) unsigned short reg1[TM * DIN];  // W halves; anchor buf B
  __shared__ __align__(16) float ldsa2[SSIZE];

  const int tid = threadIdx.x;
  const int lane = tid & 63;
  const int l15 = lane & 15;
  const int lhi = lane >> 4;
  const int n0 = blockIdx.x * TM;
  const int rbase = (tid >> 6) * 16;

  for (int i = tid; i < SSIZE; i += 256) ldsa2[i] = a2[i];

  // ---- x rows -> bf16 A-fragments (global -> reg) ----
  short8 af[4];
#pragma unroll
  for (int kk = 0; kk < 4; ++kk) {
    const float* p = x + (size_t)(n0 + rbase + l15) * DIN + kk * 32 + lhi * 8;
    float4 u = *(const float4*)p;
    float4 v = *(const float4*)(p + 4);
    short8 a;
    a[0] = f2bf(u.x); a[1] = f2bf(u.y); a[2] = f2bf(u.z); a[3] = f2bf(u.w);
    a[4] = f2bf(v.x); a[5] = f2bf(v.y); a[6] = f2bf(v.z); a[7] = f2bf(v.w);
    af[kk] = a;
  }

  // ---- encode: 2 layers x 2 staged 64-col halves of W ----
#pragma unroll 1
  for (int layer = 0; layer < 2; ++layer) {
    const unsigned short* Wb = layer ? W2b : W1b;
    const float* bias = layer ? b2 : b1;
    short8 ah[4];
#pragma unroll
    for (int kk = 0; kk < 4; ++kk)
      ah[kk] = layer ? *(const short8*)&reg0[swz(rbase + l15, kk * 32 + lhi * 8)]
                     : af[kk];
#pragma unroll 1
    for (int half = 0; half < 2; ++half) {
      stage64(Wb + (size_t)(half * 64) * DIN, reg1, tid);
      __syncthreads();  // W half staged (vmcnt drained by barrier)
      float4v acc[4];
#pragma unroll
      for (int ct = 0; ct < 4; ++ct) acc[ct] = (float4v){0.f, 0.f, 0.f, 0.f};
#pragma unroll
      for (int kk = 0; kk < 4; ++kk) {
        int k = kk * 32 + lhi * 8;
#pragma unroll
        for (int ct = 0; ct < 4; ++ct) {
          short8 b = *(const short8*)&reg1[swz(ct * 16 + l15, k)];
          acc[ct] = __builtin_amdgcn_mfma_f32_16x16x32_bf16(ah[kk], b, acc[ct], 0, 0, 0);
        }
      }
      __syncthreads();  // all waves done reading reg1 before next stage
#pragma unroll
      for (int ct = 0; ct < 4; ++ct) {
        int col = half * 64 + ct * 16 + l15;
        float bv = bias[col];
#pragma unroll
        for (int j = 0; j < 4; ++j) {
          float m = mish_f(acc[ct][j] + bv);
          reg0[swz(rbase + lhi * 4 + j, col)] = f2bf(m);  // wave-private rows
        }
      }
    }
  }

  // ---- hoist x_dml B-fragments; row norm from the rounded registers ----
  short8 bx[4];
#pragma unroll
  for (int kk = 0; kk < 4; ++kk)
    bx[kk] = *(const short8*)&reg0[swz(rbase + l15, kk * 32 + lhi * 8)];
  float x2v = 0.f;
#pragma unroll
  for (int kk = 0; kk < 4; ++kk)
#pragma unroll
    for (int e = 0; e < 8; ++e) {
      float v = bf2f((unsigned short)bx[kk][e]);
      x2v = fmaf(v, v, x2v);
    }
  x2v += __shfl_xor(x2v, 16);
  x2v += __shfl_xor(x2v, 32);   // full row-norm of row rbase+l15
  __syncthreads();              // everyone done with reg0 before anchor staging

  // ---- distance + in-register logits over 16 anchor tiles of 64 ----
  float4v lacc[2];
  lacc[0] = (float4v){0.f, 0.f, 0.f, 0.f};
  lacc[1] = (float4v){0.f, 0.f, 0.f, 0.f};
  const unsigned short* wcrow = Wcb + l15 * SSIZE;

  auto dist_tile = [&](const unsigned short* buf, int t) {
    float4v acc[4];
#pragma unroll
    for (int ct = 0; ct < 4; ++ct) acc[ct] = (float4v){0.f, 0.f, 0.f, 0.f};
    __builtin_amdgcn_s_setprio(1);
#pragma unroll
    for (int kk = 0; kk < 4; ++kk) {
      int k = kk * 32 + lhi * 8;
#pragma unroll
      for (int ct = 0; ct < 4; ++ct) {
        short8 a = *(const short8*)&buf[swz(ct * 16 + l15, k)];
        acc[ct] = __builtin_amdgcn_mfma_f32_16x16x32_bf16(a, bx[kk], acc[ct], 0, 0, 0);
      }
    }
    __builtin_amdgcn_s_setprio(0);
#pragma unroll
    for (int ct = 0; ct < 4; ++ct) {
      int sb = t * TS + ct * 16 + lhi * 4;
      float4 av = *(const float4*)&ldsa2[sb];
      us4 w4 = *(const us4*)&wcrow[sb];
      unsigned short db[4];
#pragma unroll
      for (int j = 0; j < 4; ++j) {
        float sqv = fmaf(-2.f, acc[ct][j], x2v + (&av.x)[j]);
        db[j] = f2bf(sqrtf(fmaxf(sqv, 0.f)));
      }
      short8 a8 = {(short)w4[0], (short)w4[1], (short)w4[2], (short)w4[3], 0, 0, 0, 0};
      short8 b8 = {(short)db[0], (short)db[1], (short)db[2], (short)db[3], 0, 0, 0, 0};
      lacc[ct & 1] = __builtin_amdgcn_mfma_f32_16x16x32_bf16(a8, b8, lacc[ct & 1], 0, 0, 0);
    }
  };

  stage64(ancb, reg0, tid);  // tile 0
  __syncthreads();
#pragma unroll 1
  for (int tp = 0; tp < NT / 2; ++tp) {
    stage64(ancb + (size_t)(2 * tp + 1) * TS * DIN, reg1, tid);  // in flight over compute
    dist_tile(reg0, 2 * tp);
    __syncthreads();
    if (tp < NT / 2 - 1)
      stage64(ancb + (size_t)(2 * tp + 2) * TS * DIN, reg0, tid);
    dist_tile(reg1, 2 * tp + 1);
    __syncthreads();
  }
  float4v L = lacc[0] + lacc[1];

  // ---- bias + log_softmax + store (lane holds logits[lhi*4+j][row l15]) ----
  {
    const int xrow = n0 + rbase + l15;
    float v[4];
    float m4 = -1e30f;
#pragma unroll
    for (int j = 0; j < 4; ++j) {
      int o = lhi * 4 + j;
      v[j] = (o < DOUT) ? (L[j] + bc[o]) : -1e30f;
      m4 = fmaxf(m4, v[j]);
    }
    m4 = fmaxf(m4, __shfl_xor(m4, 16));
    m4 = fmaxf(m4, __shfl_xor(m4, 32));
    float es = 0.f;
#pragma unroll
    for (int j = 0; j < 4; ++j) {
      int o = lhi * 4 + j;
      es += (o < DOUT) ? __expf(v[j] - m4) : 0.f;
    }
    es += __shfl_xor(es, 16);
    es += __shfl_xor(es, 32);
    float ls = logf(es);
#pragma unroll
    for (int j = 0; j < 4; ++j) {
      int o = lhi * 4 + j;
      if (o < DOUT) out[(size_t)xrow * DOUT + o] = v[j] - m4 - ls;
    }
  }
}

extern "C" void kernel_launch(void* const* d_in, const int* in_sizes, int n_in,
                              void* d_out, int out_size, void* d_ws, size_t ws_size,
                              hipStream_t stream) {
  const float* x   = (const float*)d_in[0];
  const float* mlg = (const float*)d_in[1];
  const float* W1  = (const float*)d_in[2];
  const float* b1  = (const float*)d_in[3];
  const float* W2  = (const float*)d_in[4];
  const float* b2  = (const float*)d_in[5];
  const float* Wa  = (const float*)d_in[6];
  const float* Wc  = (const float*)d_in[7];
  const float* bc  = (const float*)d_in[8];
  float* out = (float*)d_out;

  // workspace layout (~1.41 MB total)
  unsigned short* W1b  = (unsigned short*)d_ws;        // 16384 bf16
  unsigned short* W2b  = W1b + 16384;                  // 16384 bf16
  unsigned short* Wcb  = W2b + 16384;                  // 16*1024 bf16 (zero-padded)
  unsigned short* ancb = Wcb + 16384;                  // 1024*128 bf16
  float* a2      = (float*)(ancb + SSIZE * DIN);       // 1024 f32
  float* anc_raw = a2 + SSIZE;                         // 1024*128 f32
  float* anc_h   = anc_raw + SSIZE * DIN;              // 1024*128 f32

  k_pre1<<<704, 256, 0, stream>>>(W1, W2, Wc, Wa, mlg, W1b, W2b, Wcb, anc_raw);
  k_pre2<<<512, 256, 0, stream>>>(anc_raw, W1, b1, anc_h);
  k_pre3<<<512, 256, 0, stream>>>(anc_h, W2, b2, ancb, a2);
  k_main<<<1024, 256, 0, stream>>>(x, b1, b2, bc, W1b, W2b, Wcb, ancb, a2, out);
}

// Round 9
// 102.698 us; speedup vs baseline: 1.5677x; 1.0363x over previous
//
#include <hip/hip_runtime.h>
#include <hip/hip_bf16.h>

typedef __attribute__((ext_vector_type(8))) short short8;
typedef __attribute__((ext_vector_type(4))) float float4v;
typedef __attribute__((address_space(3))) unsigned int as3u32;
typedef __attribute__((address_space(1))) unsigned int as1u32;

#define DIN 128
#define SSIZE 1024
#define MLGK 256
#define DOUT 10
#define TM 64   // x-rows per block; 4 waves x 16 rows
#define TS 64   // anchors per staged tile
#define NT 16   // anchor tiles

union pk8 { unsigned int w[4]; short8 s8; };

#if __has_builtin(__builtin_amdgcn_sqrtf)
#define fsqrt_fast __builtin_amdgcn_sqrtf
#else
#define fsqrt_fast sqrtf
#endif

__device__ inline unsigned short f2bf(float f) {  // RNE (pre-kernels)
  unsigned int u = __float_as_uint(f);
  u = (u + 0x7FFFu + ((u >> 16) & 1u)) >> 16;
  return (unsigned short)u;
}
__device__ inline float bf2f(unsigned short h) {
  return __uint_as_float(((unsigned int)h) << 16);
}
// packed RNE f32->bf16 (header path; numerically identical to f2bf)
__device__ inline unsigned int pkbf(float lo, float hi) {
  __hip_bfloat162 p = __float22bfloat162_rn(make_float2(lo, hi));
  unsigned int r;
  __builtin_memcpy(&r, &p, 4);
  return r;
}
__device__ inline float mish_f(float x) {
  if (x > 30.f) return x;
  float e = __expf(x);
  float u = 1.f + e;
  float u2 = u * u;
  return x * (u2 - 1.f) / (u2 + 1.f);
}
// element-index XOR swizzle; identical to the chunk-XOR used by stage64
__device__ inline int swz(int row, int col) {
  return row * DIN + (col ^ ((row & 7) << 3));
}

// Stage a 64x128 bf16 tile (row stride DIN) into a 16KB LDS region via
// global_load_lds width=16. LDS dest LINEAR in lane order (rule #21); the XOR
// swizzle is applied by permuting the GLOBAL source chunk.
__device__ inline void stage64(const unsigned short* __restrict__ gsrc,
                               unsigned short* region, int tid) {
#pragma unroll
  for (int it = 0; it < 4; ++it) {
    int slot = it * 256 + tid;
    int r = slot >> 4;
    int c8 = (slot & 15) ^ (r & 7);
    __builtin_amdgcn_global_load_lds((const as1u32*)(gsrc + r * DIN + c8 * 8),
                                     (as3u32*)(region + slot * 8), 16, 0, 0);
  }
}

// ---------- wide precompute kernels (fp32, one element per thread) ----------

// blocks 0..191: weights -> bf16. blocks 192..703: anc_raw = tanh(Wa @ mlg).
__global__ __launch_bounds__(256) void k_pre1(
    const float* __restrict__ W1, const float* __restrict__ W2,
    const float* __restrict__ Wc, const float* __restrict__ Wa,
    const float* __restrict__ mlg,
    unsigned short* W1b, unsigned short* W2b, unsigned short* Wcb,
    float* anc_raw) {
  const int blk = blockIdx.x;
  const int tid = threadIdx.x;
  if (blk < 192) {
    int i = blk * 256 + tid;  // 49152 total
    if (i < 16384) {
      W1b[i] = f2bf(W1[i]);
    } else if (i < 32768) {
      W2b[i - 16384] = f2bf(W2[i - 16384]);
    } else {
      int j = i - 32768;  // [16][1024] padded Wc (rows >= DOUT zero)
      int o = j >> 10;
      int s = j & 1023;
      Wcb[j] = (o < DOUT) ? f2bf(Wc[o * SSIZE + s]) : (unsigned short)0;
    }
    return;
  }
  int i = (blk - 192) * 256 + tid;  // 1024*128
  int s = i >> 7, d = i & 127;
  float acc = 0.f;
  for (int k = 0; k < MLGK; ++k) acc = fmaf(Wa[s * MLGK + k], mlg[k * DIN + d], acc);
  anc_raw[i] = tanhf(acc);
}

// anc_h = mish(anc_raw @ W1^T + b1)
__global__ __launch_bounds__(256) void k_pre2(const float* __restrict__ anc_raw,
                                              const float* __restrict__ W1,
                                              const float* __restrict__ b1,
                                              float* anc_h) {
  int i = blockIdx.x * 256 + threadIdx.x;  // 1024*128
  int r = i >> 7, d = i & 127;
  float acc = 0.f;
  const float* a = anc_raw + r * DIN;
  const float* w = W1 + d * DIN;
  for (int k = 0; k < DIN; ++k) acc = fmaf(a[k], w[k], acc);
  anc_h[i] = mish_f(acc + b1[d]);
}

// ancb = bf16(mish(anc_h @ W2^T + b2)); a2 = rownorm2 of the ROUNDED values.
// 2 anchor rows per block (256 threads = 2 x 128 cols).
__global__ __launch_bounds__(256) void k_pre3(const float* __restrict__ anc_h,
                                              const float* __restrict__ W2,
                                              const float* __restrict__ b2,
                                              unsigned short* ancb, float* a2) {
  __shared__ float part[4];
  const int tid = threadIdx.x;
  const int row = blockIdx.x * 2 + (tid >> 7);
  const int d = tid & 127;
  float acc = 0.f;
  const float* a = anc_h + (size_t)row * DIN;
  const float* w = W2 + d * DIN;
  for (int k = 0; k < DIN; ++k) acc = fmaf(a[k], w[k], acc);
  unsigned short mb = f2bf(mish_f(acc + b2[d]));
  ancb[(size_t)row * DIN + d] = mb;
  float v = bf2f(mb);
  float p = v * v;
  p += __shfl_xor(p, 1);  p += __shfl_xor(p, 2);  p += __shfl_xor(p, 4);
  p += __shfl_xor(p, 8);  p += __shfl_xor(p, 16); p += __shfl_xor(p, 32);
  if ((tid & 63) == 0) part[tid >> 6] = p;
  __syncthreads();
  if (tid == 0)   a2[row]     = part[0] + part[1];
  if (tid == 128) a2[row]     = part[2] + part[3];
}

// ---------- fused main kernel ----------
// 4 waves x 16 x-rows; W/anchor tiles double-buffered via global_load_lds.
// Distance MFMA computes dist^T; logits accumulate in-register via zero-padded
// fragments; sqrt = v_sqrt_f32; all packs via __float22bfloat162_rn (RNE).
// LDS exactly 32 KB -> 5 blocks/CU (20 waves/CU).

__global__ __launch_bounds__(256, 5) void k_main(
    const float* __restrict__ x, const float* __restrict__ b1,
    const float* __restrict__ b2, const float* __restrict__ bc,
    const unsigned short* __restrict__ W1b, const unsigned short* __restrict__ W2b,
    const unsigned short* __restrict__ Wcb, const unsigned short* __restrict__ ancb,
    const float* __restrict__ a2, float* __restrict__ out) {
  __shared__ __align__(16) unsigned short reg0[TM * DIN];  // h/x_dml; anchor buf A
  __shared__ __align__(16) unsigned short reg1[TM * DIN];  // W halves; anchor buf B

  const int tid = threadIdx.x;
  const int lane = tid & 63;
  const int l15 = lane & 15;
  const int lhi = lane >> 4;
  const int n0 = blockIdx.x * TM;
  const int rbase = (tid >> 6) * 16;

  // ---- x rows -> bf16 A-fragments (global -> reg) ----
  short8 af[4];
#pragma unroll
  for (int kk = 0; kk < 4; ++kk) {
    const float* p = x + (size_t)(n0 + rbase + l15) * DIN + kk * 32 + lhi * 8;
    float4 u = *(const float4*)p;
    float4 v = *(const float4*)(p + 4);
    pk8 a;
    a.w[0] = pkbf(u.x, u.y);
    a.w[1] = pkbf(u.z, u.w);
    a.w[2] = pkbf(v.x, v.y);
    a.w[3] = pkbf(v.z, v.w);
    af[kk] = a.s8;
  }

  // ---- encode: 2 layers x 2 staged 64-col halves of W ----
#pragma unroll 1
  for (int layer = 0; layer < 2; ++layer) {
    const unsigned short* Wb = layer ? W2b : W1b;
    const float* bias = layer ? b2 : b1;
    short8 ah[4];
#pragma unroll
    for (int kk = 0; kk < 4; ++kk)
      ah[kk] = layer ? *(const short8*)&reg0[swz(rbase + l15, kk * 32 + lhi * 8)]
                     : af[kk];
#pragma unroll 1
    for (int half = 0; half < 2; ++half) {
      stage64(Wb + (size_t)(half * 64) * DIN, reg1, tid);
      __syncthreads();  // W half staged (vmcnt drained by barrier)
      float4v acc[4];
#pragma unroll
      for (int ct = 0; ct < 4; ++ct) acc[ct] = (float4v){0.f, 0.f, 0.f, 0.f};
#pragma unroll
      for (int kk = 0; kk < 4; ++kk) {
        int k = kk * 32 + lhi * 8;
#pragma unroll
        for (int ct = 0; ct < 4; ++ct) {
          short8 b = *(const short8*)&reg1[swz(ct * 16 + l15, k)];
          acc[ct] = __builtin_amdgcn_mfma_f32_16x16x32_bf16(ah[kk], b, acc[ct], 0, 0, 0);
        }
      }
      __syncthreads();  // all waves done reading reg1 before next stage
#pragma unroll
      for (int ct = 0; ct < 4; ++ct) {
        int col = half * 64 + ct * 16 + l15;
        float bv = bias[col];
        float m0 = mish_f(acc[ct][0] + bv);
        float m1 = mish_f(acc[ct][1] + bv);
        float m2 = mish_f(acc[ct][2] + bv);
        float m3 = mish_f(acc[ct][3] + bv);
        unsigned int w01 = pkbf(m0, m1);
        unsigned int w23 = pkbf(m2, m3);
        int r0 = rbase + lhi * 4;
        reg0[swz(r0 + 0, col)] = (unsigned short)(w01 & 0xffff);
        reg0[swz(r0 + 1, col)] = (unsigned short)(w01 >> 16);
        reg0[swz(r0 + 2, col)] = (unsigned short)(w23 & 0xffff);
        reg0[swz(r0 + 3, col)] = (unsigned short)(w23 >> 16);
      }
    }
  }

  // ---- hoist x_dml B-fragments; row norm from the rounded registers ----
  short8 bx[4];
#pragma unroll
  for (int kk = 0; kk < 4; ++kk)
    bx[kk] = *(const short8*)&reg0[swz(rbase + l15, kk * 32 + lhi * 8)];
  float x2v = 0.f;
#pragma unroll
  for (int kk = 0; kk < 4; ++kk)
#pragma unroll
    for (int e = 0; e < 8; ++e) {
      float v = bf2f((unsigned short)bx[kk][e]);
      x2v = fmaf(v, v, x2v);
    }
  x2v += __shfl_xor(x2v, 16);
  x2v += __shfl_xor(x2v, 32);   // full row-norm of row rbase+l15
  __syncthreads();              // everyone done with reg0 before anchor staging

  // ---- distance + in-register logits over 16 anchor tiles of 64 ----
  float4v lacc[2];
  lacc[0] = (float4v){0.f, 0.f, 0.f, 0.f};
  lacc[1] = (float4v){0.f, 0.f, 0.f, 0.f};
  const unsigned short* wcrow = Wcb + l15 * SSIZE;

  auto dist_tile = [&](const unsigned short* buf, int t) {
    float4v acc[4];
#pragma unroll
    for (int ct = 0; ct < 4; ++ct) acc[ct] = (float4v){0.f, 0.f, 0.f, 0.f};
    __builtin_amdgcn_s_setprio(1);
#pragma unroll
    for (int kk = 0; kk < 4; ++kk) {
      int k = kk * 32 + lhi * 8;
#pragma unroll
      for (int ct = 0; ct < 4; ++ct) {
        short8 a = *(const short8*)&buf[swz(ct * 16 + l15, k)];
        acc[ct] = __builtin_amdgcn_mfma_f32_16x16x32_bf16(a, bx[kk], acc[ct], 0, 0, 0);
      }
    }
    __builtin_amdgcn_s_setprio(0);
#pragma unroll
    for (int ct = 0; ct < 4; ++ct) {
      int sb = t * TS + ct * 16 + lhi * 4;
      float4 av = *(const float4*)&a2[sb];        // 4 KB, L1-hot
      uint2 wv = *(const uint2*)&wcrow[sb];       // 4 bf16 Wc weights
      float d0 = fsqrt_fast(fmaxf(fmaf(-2.f, acc[ct][0], x2v + av.x), 0.f));
      float d1 = fsqrt_fast(fmaxf(fmaf(-2.f, acc[ct][1], x2v + av.y), 0.f));
      float d2 = fsqrt_fast(fmaxf(fmaf(-2.f, acc[ct][2], x2v + av.z), 0.f));
      float d3 = fsqrt_fast(fmaxf(fmaf(-2.f, acc[ct][3], x2v + av.w), 0.f));
      pk8 A, B;
      A.w[0] = wv.x; A.w[1] = wv.y; A.w[2] = 0u; A.w[3] = 0u;
      B.w[0] = pkbf(d0, d1);
      B.w[1] = pkbf(d2, d3);
      B.w[2] = 0u; B.w[3] = 0u;
      lacc[ct & 1] = __builtin_amdgcn_mfma_f32_16x16x32_bf16(A.s8, B.s8, lacc[ct & 1], 0, 0, 0);
    }
  };

  stage64(ancb, reg0, tid);  // tile 0
  __syncthreads();
#pragma unroll 1
  for (int tp = 0; tp < NT / 2; ++tp) {
    stage64(ancb + (size_t)(2 * tp + 1) * TS * DIN, reg1, tid);  // in flight over compute
    dist_tile(reg0, 2 * tp);
    __syncthreads();
    if (tp < NT / 2 - 1)
      stage64(ancb + (size_t)(2 * tp + 2) * TS * DIN, reg0, tid);
    dist_tile(reg1, 2 * tp + 1);
    __syncthreads();
  }
  float4v L = lacc[0] + lacc[1];

  // ---- bias + log_softmax + store (lane holds logits[lhi*4+j][row l15]) ----
  {
    const int xrow = n0 + rbase + l15;
    float v[4];
    float m4 = -1e30f;
#pragma unroll
    for (int j = 0; j < 4; ++j) {
      int o = lhi * 4 + j;
      v[j] = (o < DOUT) ? (L[j] + bc[o]) : -1e30f;
      m4 = fmaxf(m4, v[j]);
    }
    m4 = fmaxf(m4, __shfl_xor(m4, 16));
    m4 = fmaxf(m4, __shfl_xor(m4, 32));
    float es = 0.f;
#pragma unroll
    for (int j = 0; j < 4; ++j) {
      int o = lhi * 4 + j;
      es += (o < DOUT) ? __expf(v[j] - m4) : 0.f;
    }
    es += __shfl_xor(es, 16);
    es += __shfl_xor(es, 32);
    float ls = logf(es);
#pragma unroll
    for (int j = 0; j < 4; ++j) {
      int o = lhi * 4 + j;
      if (o < DOUT) out[(size_t)xrow * DOUT + o] = v[j] - m4 - ls;
    }
  }
}

extern "C" void kernel_launch(void* const* d_in, const int* in_sizes, int n_in,
                              void* d_out, int out_size, void* d_ws, size_t ws_size,
                              hipStream_t stream) {
  const float* x   = (const float*)d_in[0];
  const float* mlg = (const float*)d_in[1];
  const float* W1  = (const float*)d_in[2];
  const float* b1  = (const float*)d_in[3];
  const float* W2  = (const float*)d_in[4];
  const float* b2  = (const float*)d_in[5];
  const float* Wa  = (const float*)d_in[6];
  const float* Wc  = (const float*)d_in[7];
  const float* bc  = (const float*)d_in[8];
  float* out = (float*)d_out;

  // workspace layout (~1.41 MB total)
  unsigned short* W1b  = (unsigned short*)d_ws;        // 16384 bf16
  unsigned short* W2b  = W1b + 16384;                  // 16384 bf16
  unsigned short* Wcb  = W2b + 16384;                  // 16*1024 bf16 (zero-padded)
  unsigned short* ancb = Wcb + 16384;                  // 1024*128 bf16
  float* a2      = (float*)(ancb + SSIZE * DIN);       // 1024 f32
  float* anc_raw = a2 + SSIZE;                         // 1024*128 f32
  float* anc_h   = anc_raw + SSIZE * DIN;              // 1024*128 f32

  k_pre1<<<704, 256, 0, stream>>>(W1, W2, Wc, Wa, mlg, W1b, W2b, Wcb, anc_raw);
  k_pre2<<<512, 256, 0, stream>>>(anc_raw, W1, b1, anc_h);
  k_pre3<<<512, 256, 0, stream>>>(anc_h, W2, b2, ancb, a2);
  k_main<<<1024, 256, 0, stream>>>(x, b1, b2, bc, W1b, W2b, Wcb, ancb, a2, out);
}